// Round 8
// baseline (244.741 us; speedup 1.0000x reference)
//
#include <hip/hip_runtime.h>
#include <cstdint>

// Problem constants: B=4, S=1024, D=768, H=12, dh=64
#define BB 4
#define SS 1024
#define DD 768
#define HH 12
#define DH 64

typedef unsigned short u16;
typedef unsigned int   u32;
typedef __attribute__((ext_vector_type(8))) short bf16x8;
typedef __attribute__((ext_vector_type(4))) float f32x4;
typedef __attribute__((ext_vector_type(16))) float f32x16;

// fp32 -> bf16 RNE (finite values)
__device__ __forceinline__ u16 f2bf(float f) {
    u32 u = __float_as_uint(f);
    u += 0x7fffu + ((u >> 16) & 1u);
    return (u16)(u >> 16);
}
__device__ __forceinline__ float b2f(u32 lo16) {
    return __uint_as_float(lo16 << 16);
}

// 2^x via v_exp_f32 (gfx950 exp is base-2)
__device__ __forceinline__ float fast_exp2(float x) {
    return __builtin_amdgcn_exp2f(x);
}

// pack two f32 -> packed bf16x2. gfx950 has V_CVT_PK_BF16_F32.
#if __has_builtin(__builtin_amdgcn_cvt_pk_bf16_f32)
__device__ __forceinline__ u32 pack2(float a, float b) {
    auto r = __builtin_amdgcn_cvt_pk_bf16_f32(a, b);
    u32 v; __builtin_memcpy(&v, &r, 4); return v;
}
#else
__device__ __forceinline__ u32 pack2(float a, float b) {
    return (u32)f2bf(a) | ((u32)f2bf(b) << 16);
}
#endif

// async global->LDS, 16 B per lane. GLOBAL pointer is PER-LANE; LDS dest is
// wave-uniform base, HW adds lane*16 (m104/m108).
#define ASYNC16(gp, lp) __builtin_amdgcn_global_load_lds( \
    (const __attribute__((address_space(1))) void*)(gp),  \
    (__attribute__((address_space(3))) void*)(lp), 16, 0, 0)

// ---------------- MFMA GEMM body (NT: A[M,K], B[N,K], both K-contiguous bf16) ----
template<int BM_, int BN_, class Epi>
__device__ __forceinline__ void mfma_gemm(
    const u16* __restrict__ A, const u16* __restrict__ B,
    int K, int lda, int ldb, int m0, int n0, const Epi& epi)
{
    constexpr int MI = BM_ / 32;
    constexpr int NJ = BN_ / 32;
    __shared__ u16 Alds[BM_ * 32];
    __shared__ u16 Blds[BN_ * 32];

    const int tid  = threadIdx.x;
    const int wave = tid >> 6;
    const int lane = tid & 63;
    const int wr = wave >> 1, wc = wave & 1;

    const int ar = lane >> 2;
    const int ac = (lane & 3) * 8;

    f32x4 acc[MI][NJ] = {};

    for (int k0 = 0; k0 < K; k0 += 32) {
        __syncthreads();
#pragma unroll
        for (int j = 0; j < BM_ / 64; ++j) {
            const int rb = wave * (BM_ / 4) + j * 16;
            ASYNC16(A + (size_t)(m0 + rb + ar) * lda + k0 + ac, &Alds[rb * 32]);
        }
#pragma unroll
        for (int j = 0; j < BN_ / 64; ++j) {
            const int rb = wave * (BN_ / 4) + j * 16;
            ASYNC16(B + (size_t)(n0 + rb + ar) * ldb + k0 + ac, &Blds[rb * 32]);
        }
        __syncthreads();

        bf16x8 af[MI], bfr[NJ];
#pragma unroll
        for (int mi = 0; mi < MI; ++mi)
            af[mi] = *(const bf16x8*)&Alds[(wr * (BM_ / 2) + mi * 16 + (lane & 15)) * 32 + (lane >> 4) * 8];
#pragma unroll
        for (int nj = 0; nj < NJ; ++nj)
            bfr[nj] = *(const bf16x8*)&Blds[(wc * (BN_ / 2) + nj * 16 + (lane & 15)) * 32 + (lane >> 4) * 8];
#pragma unroll
        for (int mi = 0; mi < MI; ++mi)
#pragma unroll
            for (int nj = 0; nj < NJ; ++nj)
                acc[mi][nj] = __builtin_amdgcn_mfma_f32_16x16x32_bf16(
                    af[mi], bfr[nj], acc[mi][nj], 0, 0, 0);
    }

#pragma unroll
    for (int mi = 0; mi < MI; ++mi)
#pragma unroll
        for (int nj = 0; nj < NJ; ++nj)
#pragma unroll
            for (int r = 0; r < 4; ++r)
                epi(m0 + wr * (BM_ / 2) + mi * 16 + (lane >> 4) * 4 + r,
                    n0 + wc * (BN_ / 2) + nj * 16 + (lane & 15),
                    acc[mi][nj][r]);
}

// padded Clds row length (u16)
#define CPAD 136

// ---------------- qkv GEMM (custom, LDS-coalesced epilogue) ----------------
__global__ __launch_bounds__(256) void qkv_gemm_kernel(
    const u16* __restrict__ xb, const u16* __restrict__ Wt,
    const float* __restrict__ bias,
    u16* __restrict__ qb, u16* __restrict__ kb, u16* __restrict__ vb)
{
    __shared__ u16 Alds[128 * 32];
    __shared__ u16 Blds[128 * 32];
    __shared__ u16 Clds[128 * CPAD];

    const int tid  = threadIdx.x;
    const int wave = tid >> 6;
    const int lane = tid & 63;
    const int wr = wave >> 1, wc = wave & 1;
    const int ar = lane >> 2;
    const int ac = (lane & 3) * 8;
    const int m0 = blockIdx.y * 128, n0 = blockIdx.x * 128;

    f32x4 acc[4][4] = {};

    for (int k0 = 0; k0 < DD; k0 += 32) {
        __syncthreads();
#pragma unroll
        for (int j = 0; j < 2; ++j) {
            const int rb = wave * 32 + j * 16;
            ASYNC16(xb + (size_t)(m0 + rb + ar) * DD + k0 + ac, &Alds[rb * 32]);
            ASYNC16(Wt + (size_t)(n0 + rb + ar) * DD + k0 + ac, &Blds[rb * 32]);
        }
        __syncthreads();

        bf16x8 af[4], bfr[4];
#pragma unroll
        for (int mi = 0; mi < 4; ++mi)
            af[mi] = *(const bf16x8*)&Alds[(wr * 64 + mi * 16 + (lane & 15)) * 32 + (lane >> 4) * 8];
#pragma unroll
        for (int nj = 0; nj < 4; ++nj)
            bfr[nj] = *(const bf16x8*)&Blds[(wc * 64 + nj * 16 + (lane & 15)) * 32 + (lane >> 4) * 8];
#pragma unroll
        for (int mi = 0; mi < 4; ++mi)
#pragma unroll
            for (int nj = 0; nj < 4; ++nj)
                acc[mi][nj] = __builtin_amdgcn_mfma_f32_16x16x32_bf16(
                    af[mi], bfr[nj], acc[mi][nj], 0, 0, 0);
    }

    const int c  = n0 / DD;
    const int w0 = n0 - c * DD;
    const int hA = w0 >> 6;
    const float qs = (c == 0) ? 0.125f : 1.0f;
#pragma unroll
    for (int mi = 0; mi < 4; ++mi)
#pragma unroll
        for (int nj = 0; nj < 4; ++nj)
#pragma unroll
            for (int r = 0; r < 4; ++r) {
                const int row = wr * 64 + mi * 16 + (lane >> 4) * 4 + r;
                const int col = wc * 64 + nj * 16 + (lane & 15);
                Clds[row * CPAD + col] = f2bf((acc[mi][nj][r] + bias[n0 + col]) * qs);
            }
    __syncthreads();

    u16* const dst = (c == 0) ? qb : (c == 1) ? kb : vb;
    const int b = m0 >> 10;
#pragma unroll
    for (int j = 0; j < 8; ++j) {
        const int idx = j * 256 + tid;
        const int row = idx >> 4, u4 = idx & 15;
        const int half = u4 >> 3, d8 = u4 & 7;
        const int h = hA + half;
        const int s = (m0 + row) & 1023;
        const uint4 v = *(const uint4*)&Clds[row * CPAD + half * 64 + d8 * 8];
        *(uint4*)&dst[(((size_t)(b * HH + h) << 10) + s) * DH + d8 * 8] = v;
    }
}

// ---------------- vb -> vt transpose (per bh: 1024x64 -> 64x1024) ----------
__global__ __launch_bounds__(256) void vtrans_kernel(
    const u16* __restrict__ vb, u16* __restrict__ vt)
{
    __shared__ u16 t[64 * 72];
    const int tid = threadIdx.x;
    const int bh = blockIdx.y;
    const int s0 = blockIdx.x * 64;
    const u16* src = vb + ((size_t)bh << 16) + (size_t)s0 * DH;

#pragma unroll
    for (int j = 0; j < 2; ++j) {
        const int idx = j * 256 + tid;
        const int row = idx >> 3, u4 = idx & 7;
        *(uint4*)&t[row * 72 + u4 * 8] = *(const uint4*)&src[row * DH + u4 * 8];
    }
    __syncthreads();

#pragma unroll
    for (int j = 0; j < 2; ++j) {
        const int idx = j * 256 + tid;
        const int d = idx >> 3, u4 = idx & 7;
        u16 tmp[8];
#pragma unroll
        for (int i = 0; i < 8; ++i) tmp[i] = t[(u4 * 8 + i) * 72 + d];
        *(uint4*)&vt[((size_t)bh * DH + d) * SS + s0 + u4 * 8] = *(const uint4*)tmp;
    }
}

// ---------------- qk GEMM (custom, LDS-coalesced epilogue) -----------------
__global__ __launch_bounds__(256) void qk_gemm_kernel(
    const u16* __restrict__ qb, const u16* __restrict__ kb,
    u16* __restrict__ attn, int bh0)
{
    __shared__ u16 Alds[128 * 32];
    __shared__ u16 Blds[128 * 32];
    __shared__ u16 Clds[128 * CPAD];

    const int tid  = threadIdx.x;
    const int wave = tid >> 6;
    const int lane = tid & 63;
    const int wr = wave >> 1, wc = wave & 1;
    const int ar = lane >> 2;
    const int ac = (lane & 3) * 8;
    const int m0 = blockIdx.y * 128, n0 = blockIdx.x * 128;

    const int bhL = blockIdx.z;
    const u16* A = qb + (size_t)(bh0 + bhL) * SS * DH;
    const u16* B = kb + (size_t)(bh0 + bhL) * SS * DH;
    u16* C = attn + (size_t)bhL * SS * SS;

    f32x4 acc[4][4] = {};

#pragma unroll
    for (int k0 = 0; k0 < DH; k0 += 32) {
        __syncthreads();
#pragma unroll
        for (int j = 0; j < 2; ++j) {
            const int rb = wave * 32 + j * 16;
            ASYNC16(A + (size_t)(m0 + rb + ar) * DH + k0 + ac, &Alds[rb * 32]);
            ASYNC16(B + (size_t)(n0 + rb + ar) * DH + k0 + ac, &Blds[rb * 32]);
        }
        __syncthreads();

        bf16x8 af[4], bfr[4];
#pragma unroll
        for (int mi = 0; mi < 4; ++mi)
            af[mi] = *(const bf16x8*)&Alds[(wr * 64 + mi * 16 + (lane & 15)) * 32 + (lane >> 4) * 8];
#pragma unroll
        for (int nj = 0; nj < 4; ++nj)
            bfr[nj] = *(const bf16x8*)&Blds[(wc * 64 + nj * 16 + (lane & 15)) * 32 + (lane >> 4) * 8];
#pragma unroll
        for (int mi = 0; mi < 4; ++mi)
#pragma unroll
            for (int nj = 0; nj < 4; ++nj)
                acc[mi][nj] = __builtin_amdgcn_mfma_f32_16x16x32_bf16(
                    af[mi], bfr[nj], acc[mi][nj], 0, 0, 0);
    }

#pragma unroll
    for (int mi = 0; mi < 4; ++mi)
#pragma unroll
        for (int nj = 0; nj < 4; ++nj)
#pragma unroll
            for (int r = 0; r < 4; ++r) {
                const int row = wr * 64 + mi * 16 + (lane >> 4) * 4 + r;
                const int col = wc * 64 + nj * 16 + (lane & 15);
                Clds[row * CPAD + col] = f2bf(acc[mi][nj][r]);
            }
    __syncthreads();

#pragma unroll
    for (int j = 0; j < 8; ++j) {
        const int idx = j * 256 + tid;
        const int row = idx >> 4, u4 = idx & 15;
        *(uint4*)&C[(size_t)(m0 + row) * SS + n0 + u4 * 8] =
            *(const uint4*)&Clds[row * CPAD + u4 * 8];
    }
}

// ---------------- pv (64x64 tile) ------------------------------------------
__global__ __launch_bounds__(256) void pv_gemm_kernel(
    const u16* __restrict__ attn2, const u16* __restrict__ vt,
    u16* __restrict__ ctx, int bh0)
{
    const int bhL = blockIdx.z;
    const int bh = bh0 + bhL;
    const int b = bh / HH, h = bh % HH;
    const u16* A = attn2 + (size_t)bhL * SS * SS;
    const u16* B = vt + (size_t)bh * DH * SS;
    u16* C = ctx + (size_t)b * SS * DD + h * DH;
    struct Epi {
        u16* C;
        __device__ void operator()(int m, int n, float v) const {
            C[(size_t)m * DD + n] = f2bf(v);
        }
    } epi{C};
    mfma_gemm<64, 64>(A, B, SS, SS, SS, blockIdx.y * 64, 0, epi);
}

// ---------------- proj (template) ------------------------------------------
__global__ __launch_bounds__(256) void proj_gemm_kernel(
    const u16* __restrict__ ctx, const u16* __restrict__ Wt,
    const float* __restrict__ bias, float* __restrict__ out)
{
    struct Epi {
        float* out; const float* bias;
        __device__ void operator()(int m, int n, float v) const {
            out[(size_t)m * DD + n] = v + bias[n];
        }
    } epi{out, bias};
    mfma_gemm<128, 64>(ctx, Wt, DD, DD, DD, blockIdx.y * 128, blockIdx.x * 64, epi);
}

// ---------------- mix + softmax (32x32x16 MFMA + shfl_xor exchange) ---------
// Logical row r (k-pos) = 16 u16 (32 B): h0..h11 + zeros at 12..15.
// Physical: block=(r&3) [stride BLKU=4112 u16: 8224B == 32B mod 128B], inner
// =(r>>2) [stride 32B], XOR-half on (inner&1). All access classes hit 8
// distinct start banks x 2 lanes per 16-lane phase = 2-way = free (m136).
// Per wave (owns k-range [wave*256,+256), 8 chunks of 32 pos):
//  mix1: ONE v_mfma_32x32x16 per chunk. D regs 0-7 (row=(j&3)+8*(j>>2)+4*hi):
//    lo lanes g{0-3,8-11}, hi lanes g{4-7,12-15(zero->exp=1)}.
//    exp2 -> pack -> P^ kept in REGISTERS (Rc[8][4]) across the den barrier.
//  mix2 B-frag via __shfl_xor(.,32) (defined semantics; the R7 permlane asm
//    direction was unverified and failed): word0=hi?s2:w0, word1=hi?s3:w1,
//    word2=s0, word3=s1. Junk only ever lands in k>=12 (A2 zeros kill it).
//  mix2 D -> pack -> LDS writeback (lo: 2 b64, hi: 1 b64) -> stream-out.
// 2 barriers total (den reduce); stage-in/mix/stream-out all wave-local
// (same-wave LDS ops execute in order).
#define BLKU 4112

__device__ __forceinline__ int physIdx(int r, int half) {
    // u16 index of the 16B-unit `half` of logical row r
    return (r & 3) * BLKU + (r >> 2) * 16 + ((half ^ ((r >> 2) & 1)) << 3);
}

__global__ __launch_bounds__(256) void mix_softmax_kernel(
    const u16* __restrict__ attn, u16* __restrict__ attn2,
    const float* __restrict__ Wl, const float* __restrict__ bl,
    const float* __restrict__ Ww, const float* __restrict__ bw)
{
    __shared__ u16 buf[4 * BLKU];          // 32.9 KB -> 4 blocks/CU
    __shared__ float wsum[4][16];
    __shared__ float invd[16];

    const int tid  = threadIdx.x;
    const int wave = tid >> 6;
    const int lane = tid & 63;
    const int l31  = lane & 31;
    const int hi   = lane >> 5;
    const int bL = blockIdx.x >> 10;
    const int qi = blockIdx.x & (SS - 1);
    const size_t gbase = ((size_t)bL * HH * SS + qi) * SS + tid * 4;

    // ---- stage-in: 12 uint2 loads, register transpose, vector LDS writes
    {
        uint2 src[HH];
#pragma unroll
        for (int h = 0; h < HH; ++h)
            src[h] = *(const uint2*)&attn[gbase + (size_t)h * SS * SS];

#pragma unroll
        for (int i = 0; i < 4; ++i) {
            const u32 sel = (i & 1) ? 0x07060302u : 0x05040100u;
            u32 w[6];
#pragma unroll
            for (int j = 0; j < 6; ++j) {
                const u32 lo = (i < 2) ? src[2 * j].x     : src[2 * j].y;
                const u32 hh = (i < 2) ? src[2 * j + 1].x : src[2 * j + 1].y;
                w[j] = __builtin_amdgcn_perm(hh, lo, sel);
            }
            uint4 q0; q0.x = w[0]; q0.y = w[1]; q0.z = w[2]; q0.w = w[3];
            uint4 q1; q1.x = w[4]; q1.y = w[5]; q1.z = 0u;   q1.w = 0u;
            const int r = 4 * tid + i;
            *(uint4*)&buf[physIdx(r, 0)] = q0;
            *(uint4*)&buf[physIdx(r, 1)] = q1;
        }
    }

    // A1 frag (32x32x16): A[m=g][k=h] = Wl[h][g]*log2e; m=l31, k=hi*8+j
    bf16x8 a1;
    {
        u16 t[8];
#pragma unroll
        for (int j = 0; j < 8; ++j) {
            const int k = hi * 8 + j;
            t[j] = (k < HH && l31 < HH) ? f2bf(Wl[k * HH + l31] * 1.44269504f) : (u16)0;
        }
        __builtin_memcpy(&a1, t, 16);
    }
    // C1: c[r] = bl[row]*log2e, row = (r&3)+8*(r>>2)+4*hi
    f32x16 c1;
#pragma unroll
    for (int r = 0; r < 16; ++r) {
        const int row = (r & 3) + 8 * (r >> 2) + 4 * hi;
        c1[r] = (row < HH) ? bl[row] * 1.44269504f : 0.f;
    }

    const int posbase = wave * 256;

    // ---- mix1 + exp; P^ packed bf16 kept in registers (wave-local rows)
    u32 Rc[8][4];
    float dacc[8] = {0.f, 0.f, 0.f, 0.f, 0.f, 0.f, 0.f, 0.f};
#pragma unroll
    for (int c = 0; c < 8; ++c) {
        const int r = posbase + c * 32 + l31;
        const bf16x8 bfrag = *(const bf16x8*)&buf[physIdx(r, hi)];
        const f32x16 d = __builtin_amdgcn_mfma_f32_32x32x16_bf16(a1, bfrag, c1, 0, 0, 0);
        float e[8];
#pragma unroll
        for (int j = 0; j < 8; ++j) e[j] = fast_exp2(d[j]);
        dacc[0] += e[0]; dacc[1] += e[1]; dacc[2] += e[2]; dacc[3] += e[3];
        if (lane < 32) {
            dacc[4] += e[4]; dacc[5] += e[5]; dacc[6] += e[6]; dacc[7] += e[7];
        }
        Rc[c][0] = pack2(e[0], e[1]);
        Rc[c][1] = pack2(e[2], e[3]);
        Rc[c][2] = pack2(e[4], e[5]);
        Rc[c][3] = pack2(e[6], e[7]);
    }

    // ---- den reduce: butterfly within 32-lane halves, cross-wave via LDS
#pragma unroll
    for (int off = 1; off < 32; off <<= 1) {
#pragma unroll
        for (int j = 0; j < 8; ++j) dacc[j] += __shfl_xor(dacc[j], off);
    }
    if (lane == 0) {
#pragma unroll
        for (int j = 0; j < 4; ++j) { wsum[wave][j] = dacc[j]; wsum[wave][8 + j] = dacc[4 + j]; }
    }
    if (lane == 32) {
#pragma unroll
        for (int j = 0; j < 4; ++j) wsum[wave][4 + j] = dacc[j];
    }
    __syncthreads();
    if (tid < HH)
        invd[tid] = 1.0f / (wsum[0][tid] + wsum[1][tid] + wsum[2][tid] + wsum[3][tid]);
    __syncthreads();

    // A2 frag: A[m=g2][k=g] = Ww[g][g2]*invd[g]; m=l31, k=hi*8+j
    bf16x8 a2;
    {
        u16 t[8];
#pragma unroll
        for (int j = 0; j < 8; ++j) {
            const int k = hi * 8 + j;
            t[j] = (k < HH && l31 < HH) ? f2bf(Ww[k * HH + l31] * invd[k]) : (u16)0;
        }
        __builtin_memcpy(&a2, t, 16);
    }
    f32x16 c2;
#pragma unroll
    for (int r = 0; r < 16; ++r) {
        const int row = (r & 3) + 8 * (r >> 2) + 4 * hi;
        c2[r] = (row < HH) ? bw[row] : 0.f;
    }

    // ---- mix2: B-frag assembled via shfl_xor(32); MFMA; writeback
#pragma unroll
    for (int c = 0; c < 8; ++c) {
        const u32 w0 = Rc[c][0], w1 = Rc[c][1], w2 = Rc[c][2], w3 = Rc[c][3];
        const u32 s0 = (u32)__shfl_xor((int)w0, 32);
        const u32 s1 = (u32)__shfl_xor((int)w1, 32);
        const u32 s2 = (u32)__shfl_xor((int)w2, 32);
        const u32 s3 = (u32)__shfl_xor((int)w3, 32);
        u32 bw_[4];
        bw_[0] = hi ? s2 : w0;   // k0,1  : lo g0g1   ; hi g8g9
        bw_[1] = hi ? s3 : w1;   // k2,3  : lo g2g3   ; hi g10g11
        bw_[2] = s0;             // k4,5  : lo g4g5   ; hi junk (k12,13 -> A2=0)
        bw_[3] = s1;             // k6,7  : lo g6g7   ; hi junk (k14,15 -> A2=0)
        bf16x8 b2; __builtin_memcpy(&b2, bw_, 16);
        const f32x16 d = __builtin_amdgcn_mfma_f32_32x32x16_bf16(a2, b2, c2, 0, 0, 0);

        const int r = posbase + c * 32 + l31;
        uint2 pA; pA.x = pack2(d[0], d[1]); pA.y = pack2(d[2], d[3]);
        if (lane < 32) {
            uint2 pB; pB.x = pack2(d[4], d[5]); pB.y = pack2(d[6], d[7]);
            *(uint2*)&buf[physIdx(r, 0)] = pA;       // g0-3
            *(uint2*)&buf[physIdx(r, 1)] = pB;       // g8-11
        } else {
            *(uint2*)&buf[physIdx(r, 0) + 4] = pA;   // g4-7
        }
    }

    // ---- stream-out: reverse register transpose -> 12 coalesced uint2 stores
    {
        u32 rw[4][6];
#pragma unroll
        for (int i = 0; i < 4; ++i) {
            const int r = 4 * tid + i;
            const uint4 a = *(const uint4*)&buf[physIdx(r, 0)];
            const uint2 b = *(const uint2*)&buf[physIdx(r, 1)];
            rw[i][0] = a.x; rw[i][1] = a.y; rw[i][2] = a.z;
            rw[i][3] = a.w; rw[i][4] = b.x; rw[i][5] = b.y;
        }
#pragma unroll
        for (int g = 0; g < HH; ++g) {
            const u32 sel = (g & 1) ? 0x07060302u : 0x05040100u;
            uint2 p;
            p.x = __builtin_amdgcn_perm(rw[1][g >> 1], rw[0][g >> 1], sel);
            p.y = __builtin_amdgcn_perm(rw[3][g >> 1], rw[2][g >> 1], sel);
            *(uint2*)&attn2[gbase + (size_t)g * SS * SS] = p;
        }
    }
}

// ---------------- conversion kernels ----------------

__global__ __launch_bounds__(256) void cvt_bf16_kernel(
    const float* __restrict__ in, u16* __restrict__ out, int n8)
{
    const int i = blockIdx.x * 256 + threadIdx.x;
    if (i >= n8) return;
    const float4 a = ((const float4*)in)[i * 2];
    const float4 b = ((const float4*)in)[i * 2 + 1];
    uint4 p;
    p.x = pack2(a.x, a.y); p.y = pack2(a.z, a.w);
    p.z = pack2(b.x, b.y); p.w = pack2(b.z, b.w);
    ((uint4*)out)[i] = p;
}

__global__ __launch_bounds__(256) void cvt_transpose_kernel(
    const float* __restrict__ in, u16* __restrict__ out, int R, int C)
{
    __shared__ float t[32][33];
    const int c0 = blockIdx.x * 32, r0 = blockIdx.y * 32;
    const int tr = threadIdx.x >> 3;
    const int tc = (threadIdx.x & 7) * 4;
    const float4 v = *(const float4*)&in[(size_t)(r0 + tr) * C + c0 + tc];
    t[tc + 0][tr] = v.x; t[tc + 1][tr] = v.y;
    t[tc + 2][tr] = v.z; t[tc + 3][tr] = v.w;
    __syncthreads();
    uint2 p;
    p.x = pack2(t[tr][tc + 0], t[tr][tc + 1]);
    p.y = pack2(t[tr][tc + 2], t[tr][tc + 3]);
    *(uint2*)&out[(size_t)(c0 + tr) * R + r0 + tc] = p;
}

// ---------------- launch ----------------
extern "C" void kernel_launch(void* const* d_in, const int* in_sizes, int n_in,
                              void* d_out, int out_size, void* d_ws, size_t ws_size,
                              hipStream_t stream)
{
    const float* x     = (const float*)d_in[0];
    const float* Wqkv  = (const float*)d_in[1];
    const float* bqkv  = (const float*)d_in[2];
    const float* Wl    = (const float*)d_in[3];
    const float* bl    = (const float*)d_in[4];
    const float* Ww    = (const float*)d_in[5];
    const float* bw    = (const float*)d_in[6];
    const float* Wproj = (const float*)d_in[7];
    const float* bproj = (const float*)d_in[8];
    float* out = (float*)d_out;

    // workspace (bf16 elems)
    const size_t N_XB  = (size_t)BB * SS * DD;
    const size_t N_QB  = (size_t)BB * HH * SS * DH;
    const size_t N_WT  = (size_t)DD * 3 * DD;
    const size_t N_WP  = (size_t)DD * DD;
    const size_t N_AT1 = (size_t)HH * SS * SS;

    u16* xb  = (u16*)d_ws;
    u16* qb  = xb  + N_XB;
    u16* kb  = qb  + N_QB;
    u16* vb  = kb  + N_QB;
    u16* vt  = vb  + N_QB;
    u16* ctx = vt  + N_QB;
    u16* Wqkv_t = ctx + N_XB;
    u16* Wproj_t = Wqkv_t + N_WT;
    u16* attn = Wproj_t + N_WP;

    // mix runs IN-PLACE on attn (each block reads its 12 rows fully before
    // writing them): halves the attn HBM write traffic and the workspace.
    const size_t fixed_bytes = (size_t)(N_XB * 2 + N_QB * 4 + N_WT + N_WP) * 2;
    int b_per = BB;
    while (b_per > 1 &&
           fixed_bytes + (size_t)b_per * N_AT1 * 2 > ws_size)
        b_per >>= 1;
    const int n_iter = BB / b_per;
    u16* attn2 = attn;

    const dim3 blk(256);

    // 0) conversions
    cvt_bf16_kernel<<<dim3((N_XB / 8 + 255) / 256), blk, 0, stream>>>(x, xb, (int)(N_XB / 8));
    cvt_transpose_kernel<<<dim3(3 * DD / 32, DD / 32), blk, 0, stream>>>(Wqkv, Wqkv_t, DD, 3 * DD);
    cvt_transpose_kernel<<<dim3(DD / 32, DD / 32), blk, 0, stream>>>(Wproj, Wproj_t, DD, DD);

    // 1) QKV projection (qb scaled, kb, vb) + v transpose
    qkv_gemm_kernel<<<dim3(3 * DD / 128, BB * SS / 128), blk, 0, stream>>>(
        xb, Wqkv_t, bqkv, qb, kb, vb);
    vtrans_kernel<<<dim3(SS / 64, BB * HH), blk, 0, stream>>>(vb, vt);

    for (int it = 0; it < n_iter; ++it) {
        const int bh0 = it * b_per * HH;
        // 2) logits
        qk_gemm_kernel<<<dim3(SS / 128, SS / 128, b_per * HH), blk, 0, stream>>>(
            qb, kb, attn, bh0);
        // 3) mix1 + softmax + mix2 (32x32 MFMA, register P, shfl exchange)
        mix_softmax_kernel<<<dim3(b_per * SS), blk, 0, stream>>>(
            attn, attn2, Wl, bl, Ww, bw);
        // 4) PV (64x64 tiles)
        pv_gemm_kernel<<<dim3(1, SS / 64, b_per * HH), blk, 0, stream>>>(
            attn2, vt, ctx, bh0);
    }

    // 5) output projection
    proj_gemm_kernel<<<dim3(DD / 64, BB * SS / 128), blk, 0, stream>>>(
        ctx, Wproj_t, bproj, out);
}